// Round 1
// baseline (2653.296 us; speedup 1.0000x reference)
//
#include <hip/hip_runtime.h>
#include <hip/hip_bf16.h>
#include <cstdint>
#include <cstddef>

// Model constants
#define VOCAB 32000
#define DMODEL 512
#define NLAYERS 6
#define DINNER 1024
#define DSTATE 16
#define DCONV 4
#define DTRANK 32
#define BB 2
#define LL 1024
#define ROWS (BB * LL)   // 2048

// ---------------------------------------------------------------------------
// Embedding gather: x[row,:] = embed[tokens[row],:]
__global__ __launch_bounds__(128) void embed_k(const int* __restrict__ tokens,
                                               const float* __restrict__ embed,
                                               float* __restrict__ x) {
    int row = blockIdx.x;
    int tid = threadIdx.x;
    int tok = tokens[row];
    *(float4*)(x + (size_t)row * DMODEL + tid * 4) =
        *(const float4*)(embed + (size_t)tok * DMODEL + tid * 4);
}

// ---------------------------------------------------------------------------
// Generic NT GEMM: C[M,N] = A[M,K] @ W[N,K]^T, row-major, 64x64 tile,
// 256 threads, 4x4 micro-tile. epi: 0 = none, 1 = softplus(acc + bias[col]).
__global__ __launch_bounds__(256) void gemm_nt(
    const float* __restrict__ A, int lda,
    const float* __restrict__ W, int ldw,
    float* __restrict__ C, int ldc,
    int M, int N, int K,
    const float* __restrict__ bias, int epi)
{
    __shared__ float As[16][64];
    __shared__ float Bs[16][64];
    int tid = threadIdx.x;
    int tx = tid & 15, ty = tid >> 4;
    int m0 = blockIdx.y * 64, n0 = blockIdx.x * 64;
    int lr = tid >> 2;          // 0..63 (row within tile)
    int lc = (tid & 3) * 4;     // 0,4,8,12 (k offset)
    float acc[4][4] = {};

    for (int k0 = 0; k0 < K; k0 += 16) {
        float4 a4 = *(const float4*)(A + (size_t)(m0 + lr) * lda + k0 + lc);
        float4 b4 = *(const float4*)(W + (size_t)(n0 + lr) * ldw + k0 + lc);
        As[lc + 0][lr] = a4.x; As[lc + 1][lr] = a4.y;
        As[lc + 2][lr] = a4.z; As[lc + 3][lr] = a4.w;
        Bs[lc + 0][lr] = b4.x; Bs[lc + 1][lr] = b4.y;
        Bs[lc + 2][lr] = b4.z; Bs[lc + 3][lr] = b4.w;
        __syncthreads();
#pragma unroll
        for (int k = 0; k < 16; ++k) {
            float4 av = *(const float4*)&As[k][ty * 4];
            float4 bv = *(const float4*)&Bs[k][tx * 4];
            float a_[4] = {av.x, av.y, av.z, av.w};
            float b_[4] = {bv.x, bv.y, bv.z, bv.w};
#pragma unroll
            for (int i = 0; i < 4; ++i)
#pragma unroll
                for (int j = 0; j < 4; ++j)
                    acc[i][j] += a_[i] * b_[j];
        }
        __syncthreads();
    }

#pragma unroll
    for (int i = 0; i < 4; ++i) {
        int row = m0 + ty * 4 + i;
        int col = n0 + tx * 4;
        float v[4] = {acc[i][0], acc[i][1], acc[i][2], acc[i][3]};
        if (epi == 1) {
#pragma unroll
            for (int j = 0; j < 4; ++j) {
                float t = v[j] + bias[col + j];
                v[j] = (t > 20.f) ? t : log1pf(expf(t));
            }
        }
        float4 o = {v[0], v[1], v[2], v[3]};
        *(float4*)(C + (size_t)row * ldc + col) = o;
    }
}

// ---------------------------------------------------------------------------
// Causal depthwise conv (width 4) + bias + SiLU.
// input = first half of xz [ROWS, 2*DINNER]; output xi [ROWS, DINNER]
__global__ __launch_bounds__(256) void conv_silu(const float* __restrict__ xz,
                                                 const float* __restrict__ cw,
                                                 const float* __restrict__ cb,
                                                 float* __restrict__ xi) {
    int idx = blockIdx.x * 256 + threadIdx.x;   // (b*1024+t)*1024 + d
    int d = idx & 1023;
    int t = (idx >> 10) & 1023;
    int b = idx >> 20;
    const float* base = xz + (size_t)(b * LL) * (2 * DINNER) + d;
    float acc = cb[d];
#pragma unroll
    for (int j = 0; j < DCONV; ++j) {
        int tt = t - 3 + j;
        if (tt >= 0) acc += cw[d * 4 + j] * base[(size_t)tt * (2 * DINNER)];
    }
    float s = acc / (1.f + expf(-acc));
    xi[idx] = s;
}

// ---------------------------------------------------------------------------
// Selective scan, chunked: 8 chunks x 128 steps. Block = 16 channels x 16 states.
// PASS 1: local scan from h=0, store P=prod(dA), S=h_end.
// PASS 3: scan from carry H0, reduce y over states, fuse D-skip + z-gating.
template <int PASS>
__global__ __launch_bounds__(256) void scan_k(
    const float* __restrict__ dlt, const float* __restrict__ xi,
    const float* __restrict__ dbc, const float* __restrict__ A_log,
    const float* __restrict__ Dskip, const float* __restrict__ xz,
    float* __restrict__ P, float* __restrict__ S,
    const float* __restrict__ H0, float* __restrict__ yg)
{
    __shared__ float sd[128][16], sx[128][16], sB[128][16], sC[128][16], sY[128][16];
    int c = blockIdx.x, dblk = blockIdx.y, b = blockIdx.z;
    int tid = threadIdx.x;
    int d0 = dblk * 16;
    int t0 = c * 128;

    for (int idx = tid; idx < 128 * 16; idx += 256) {
        int t = idx >> 4, i = idx & 15;
        int row = b * LL + t0 + t;
        sd[t][i] = dlt[(size_t)row * DINNER + d0 + i];
        sx[t][i] = xi[(size_t)row * DINNER + d0 + i];
        sB[t][i] = dbc[(size_t)row * 64 + DTRANK + i];
        sC[t][i] = dbc[(size_t)row * 64 + DTRANK + DSTATE + i];
    }
    __syncthreads();

    int di = tid >> 4, n = tid & 15;
    int d = d0 + di;
    float Adn = -expf(A_log[d * DSTATE + n]);
    float Dsk = Dskip[d];
    float h, ap = 1.f;
    if (PASS == 1) h = 0.f;
    else           h = H0[(size_t)(c * 2 + b) * 16384 + d * 16 + n];

    for (int t = 0; t < 128; ++t) {
        float dl = sd[t][di];
        float dA = expf(dl * Adn);
        h = dA * h + dl * sx[t][di] * sB[t][n];
        if (PASS == 1) {
            ap *= dA;
        } else {
            float p = h * sC[t][n];
            p += __shfl_xor(p, 1);
            p += __shfl_xor(p, 2);
            p += __shfl_xor(p, 4);
            p += __shfl_xor(p, 8);
            if (n == 0) sY[t][di] = p + sx[t][di] * Dsk;
        }
    }

    if (PASS == 1) {
        size_t o = (size_t)(c * 2 + b) * 16384 + d * 16 + n;
        P[o] = ap;
        S[o] = h;
    } else {
        __syncthreads();
        for (int idx = tid; idx < 128 * 16; idx += 256) {
            int t = idx >> 4, i = idx & 15;
            int row = b * LL + t0 + t;
            float z = xz[(size_t)row * (2 * DINNER) + DINNER + d0 + i];
            float y = sY[t][i];
            yg[(size_t)row * DINNER + d0 + i] = y * (z / (1.f + expf(-z)));
        }
    }
}

// Chunk-carry prefix: thread per (b,d,n) = 32768 threads.
__global__ __launch_bounds__(256) void scan_carry(const float* __restrict__ P,
                                                  const float* __restrict__ S,
                                                  float* __restrict__ H0) {
    int idx = blockIdx.x * 256 + threadIdx.x;
    float carry = 0.f;
#pragma unroll
    for (int c = 0; c < 8; ++c) {
        H0[(size_t)c * 32768 + idx] = carry;
        carry = P[(size_t)c * 32768 + idx] * carry + S[(size_t)c * 32768 + idx];
    }
}

// ---------------------------------------------------------------------------
// LayerNorm over last dim 512. One block (128 threads) per row.
__global__ __launch_bounds__(128) void lnorm(const float* __restrict__ x,
                                             const float* __restrict__ w,
                                             const float* __restrict__ bp,
                                             float* __restrict__ xn) {
    int row = blockIdx.x;
    int tid = threadIdx.x;
    float4 v = *(const float4*)(x + (size_t)row * DMODEL + tid * 4);
    float s = v.x + v.y + v.z + v.w;
    float q = v.x * v.x + v.y * v.y + v.z * v.z + v.w * v.w;
#pragma unroll
    for (int m = 1; m < 64; m <<= 1) {
        s += __shfl_xor(s, m);
        q += __shfl_xor(q, m);
    }
    __shared__ float ss[2], qq[2];
    if ((tid & 63) == 0) { ss[tid >> 6] = s; qq[tid >> 6] = q; }
    __syncthreads();
    s = ss[0] + ss[1];
    q = qq[0] + qq[1];
    float mu = s / (float)DMODEL;
    float var = q / (float)DMODEL - mu * mu;
    float r = rsqrtf(var + 1e-5f);
    int c = tid * 4;
    float4 o;
    o.x = (v.x - mu) * r * w[c + 0] + bp[c + 0];
    o.y = (v.y - mu) * r * w[c + 1] + bp[c + 1];
    o.z = (v.z - mu) * r * w[c + 2] + bp[c + 2];
    o.w = (v.w - mu) * r * w[c + 3] + bp[c + 3];
    *(float4*)(xn + (size_t)row * DMODEL + c) = o;
}

// ---------------------------------------------------------------------------
extern "C" void kernel_launch(void* const* d_in, const int* in_sizes, int n_in,
                              void* d_out, int out_size, void* d_ws, size_t ws_size,
                              hipStream_t stream) {
    const int*   tokens = (const int*)d_in[0];
    const float* embed  = (const float*)d_in[1];
    const float* inw    = (const float*)d_in[2];
    const float* cw     = (const float*)d_in[3];
    const float* cb     = (const float*)d_in[4];
    const float* xpw    = (const float*)d_in[5];
    const float* dtw    = (const float*)d_in[6];
    const float* dtb    = (const float*)d_in[7];
    const float* Alog   = (const float*)d_in[8];
    const float* Dsk    = (const float*)d_in[9];
    const float* outw   = (const float*)d_in[10];
    const float* nw     = (const float*)d_in[11];
    const float* nb     = (const float*)d_in[12];
    const float* hw     = (const float*)d_in[13];
    float* out = (float*)d_out;

    float* ws = (float*)d_ws;
    float* x   = ws;                    // ROWS*DMODEL            = 1M floats
    float* xz  = x   + (1 << 20);       // ROWS*2*DINNER          = 4M
    float* xib = xz  + (4 << 20);       // ROWS*DINNER            = 2M
    float* dbc = xib + (2 << 20);       // ROWS*64                = 128K
    float* dlt = dbc + (1 << 17);       // ROWS*DINNER            = 2M
    float* yg  = dlt + (2 << 20);       // ROWS*DINNER            = 2M
    float* xn  = yg  + (2 << 20);       // ROWS*DMODEL            = 1M
    float* Pb  = xn  + (1 << 20);       // 8*2*1024*16            = 256K
    float* Sb  = Pb  + (1 << 18);       // 256K
    float* H0  = Sb  + (1 << 18);       // 256K

    embed_k<<<ROWS, 128, 0, stream>>>(tokens, embed, x);

    for (int l = 0; l < NLAYERS; ++l) {
        const float* inw_l  = inw  + (size_t)l * 2 * DINNER * DMODEL;
        const float* cw_l   = cw   + (size_t)l * DINNER * DCONV;
        const float* cb_l   = cb   + (size_t)l * DINNER;
        const float* xpw_l  = xpw  + (size_t)l * 64 * DINNER;
        const float* dtw_l  = dtw  + (size_t)l * DINNER * DTRANK;
        const float* dtb_l  = dtb  + (size_t)l * DINNER;
        const float* Alog_l = Alog + (size_t)l * DINNER * DSTATE;
        const float* Dsk_l  = Dsk  + (size_t)l * DINNER;
        const float* outw_l = outw + (size_t)l * DMODEL * DINNER;

        // xz = x @ inw^T   [2048, 2048]
        gemm_nt<<<dim3(2 * DINNER / 64, ROWS / 64), 256, 0, stream>>>(
            x, DMODEL, inw_l, DMODEL, xz, 2 * DINNER, ROWS, 2 * DINNER, DMODEL, nullptr, 0);
        // xi = silu(causal_conv(xz[:, :DINNER]) + cb)
        conv_silu<<<(ROWS * DINNER) / 256, 256, 0, stream>>>(xz, cw_l, cb_l, xib);
        // dbc = xi @ xpw^T   [2048, 64]
        gemm_nt<<<dim3(1, ROWS / 64), 256, 0, stream>>>(
            xib, DINNER, xpw_l, DINNER, dbc, 64, ROWS, 64, DINNER, nullptr, 0);
        // delta = softplus(dbc[:, :32] @ dtw^T + dtb)   [2048, 1024]
        gemm_nt<<<dim3(DINNER / 64, ROWS / 64), 256, 0, stream>>>(
            dbc, 64, dtw_l, DTRANK, dlt, DINNER, ROWS, DINNER, DTRANK, dtb_l, 1);
        // selective scan (3 passes)
        scan_k<1><<<dim3(8, DINNER / 16, BB), 256, 0, stream>>>(
            dlt, xib, dbc, Alog_l, Dsk_l, xz, Pb, Sb, nullptr, nullptr);
        scan_carry<<<128, 256, 0, stream>>>(Pb, Sb, H0);
        scan_k<3><<<dim3(8, DINNER / 16, BB), 256, 0, stream>>>(
            dlt, xib, dbc, Alog_l, Dsk_l, xz, nullptr, nullptr, H0, yg);
        // x = yg @ outw^T   [2048, 512]
        gemm_nt<<<dim3(DMODEL / 64, ROWS / 64), 256, 0, stream>>>(
            yg, DINNER, outw_l, DINNER, x, DMODEL, ROWS, DMODEL, DINNER, nullptr, 0);
    }

    lnorm<<<ROWS, 128, 0, stream>>>(x, nw, nb, xn);
    // logits = xn @ head_w^T   [2048, 32000]
    gemm_nt<<<dim3(VOCAB / 64, ROWS / 64), 256, 0, stream>>>(
        xn, DMODEL, hw, DMODEL, out, VOCAB, ROWS, VOCAB, DMODEL, nullptr, 0);
}

// Round 2
// 1964.328 us; speedup vs baseline: 1.3507x; 1.3507x over previous
//
#include <hip/hip_runtime.h>
#include <hip/hip_bf16.h>
#include <cstdint>
#include <cstddef>

// Model constants
#define VOCAB 32000
#define DMODEL 512
#define NLAYERS 6
#define DINNER 1024
#define DSTATE 16
#define DCONV 4
#define DTRANK 32
#define BB 2
#define LL 1024
#define ROWS (BB * LL)   // 2048

typedef _Float16 half8 __attribute__((ext_vector_type(8)));
typedef float floatx4 __attribute__((ext_vector_type(4)));

// ---------------------------------------------------------------------------
// Embedding gather: x[row,:] = embed[tokens[row],:]
__global__ __launch_bounds__(128) void embed_k(const int* __restrict__ tokens,
                                               const float* __restrict__ embed,
                                               float* __restrict__ x) {
    int row = blockIdx.x;
    int tid = threadIdx.x;
    int tok = tokens[row];
    *(float4*)(x + (size_t)row * DMODEL + tid * 4) =
        *(const float4*)(embed + (size_t)tok * DMODEL + tid * 4);
}

// ---------------------------------------------------------------------------
// Split-f16 MFMA GEMM: C[M,N] = A[M,K] @ W[N,K]^T, fp32 in/out.
// Each fp32 value v = hi + lo (f16 each); C = Ah*Bh + Ah*Bl + Al*Bh
// (rel err ~2^-21). Tile BM x BN, BK=32, 256 threads = 4 waves (2x2),
// wave tile (BM/2)x(BN/2), mfma_f32_16x16x32_f16.
// LDS layout: [row][64] halves; cols 0-31 = hi, 32-63 = lo; 16B chunks
// XOR-swizzled by (row&7) -> conflict-free b128 reads/writes (G4).
template<int BM, int BN>
__global__ __launch_bounds__(256) void gemm_split(
    const float* __restrict__ A, int lda,
    const float* __restrict__ W, int ldw,
    float* __restrict__ C, int ldc,
    int K, int NBX)
{
    constexpr int FM = BM / 32;   // A frags per wave
    constexpr int FN = BN / 32;   // B frags per wave
    __shared__ __attribute__((aligned(16))) _Float16 As[BM * 64];
    __shared__ __attribute__((aligned(16))) _Float16 Bs[BN * 64];

    // bijective XCD swizzle (grid sizes all divisible by 8)
    int bid = blockIdx.x;
    int cpx = gridDim.x >> 3;
    int swz = (bid & 7) * cpx + (bid >> 3);
    int bx = swz % NBX, by = swz / NBX;
    int m0 = by * BM, n0 = bx * BN;

    int tid = threadIdx.x;
    int wid = tid >> 6, lane = tid & 63;
    int wm = wid >> 1, wn = wid & 1;
    int lr = lane & 15, lk = lane >> 4;   // row-in-frag, 16B chunk idx

    floatx4 acc[FM][FN] = {};

    constexpr int ACH = BM * 4;          // 8-float chunks in A tile
    constexpr int TOT = (BM + BN) * 4;   // total chunks per K-step

    for (int k0 = 0; k0 < K; k0 += 32) {
        // ---- stage: global fp32 -> f16 hi/lo in swizzled LDS ----
#pragma unroll
        for (int i = tid; i < TOT; i += 256) {
            bool isA = i < ACH;
            int j = isA ? i : i - ACH;
            int r = j >> 2, c8 = j & 3;
            const float* src = isA ? (A + (size_t)(m0 + r) * lda + k0 + c8 * 8)
                                   : (W + (size_t)(n0 + r) * ldw + k0 + c8 * 8);
            float4 v0 = *(const float4*)(src);
            float4 v1 = *(const float4*)(src + 4);
            float vv[8] = {v0.x, v0.y, v0.z, v0.w, v1.x, v1.y, v1.z, v1.w};
            half8 hi, lo;
#pragma unroll
            for (int e = 0; e < 8; ++e) {
                _Float16 h = (_Float16)vv[e];
                hi[e] = h;
                lo[e] = (_Float16)(vv[e] - (float)h);
            }
            _Float16* dst = (isA ? As : Bs) + r * 64;
            *(half8*)(dst + (((c8)     ^ (r & 7)) << 3)) = hi;
            *(half8*)(dst + (((c8 + 4) ^ (r & 7)) << 3)) = lo;
        }
        __syncthreads();

        // ---- fragments + 3-MFMA split accumulate ----
        half8 ah[FM], al[FM], bh[FN], bl[FN];
#pragma unroll
        for (int f = 0; f < FM; ++f) {
            int r = wm * (BM / 2) + f * 16 + lr;
            const _Float16* p = As + r * 64;
            ah[f] = *(const half8*)(p + (((lk)     ^ (r & 7)) << 3));
            al[f] = *(const half8*)(p + (((lk + 4) ^ (r & 7)) << 3));
        }
#pragma unroll
        for (int f = 0; f < FN; ++f) {
            int r = wn * (BN / 2) + f * 16 + lr;
            const _Float16* p = Bs + r * 64;
            bh[f] = *(const half8*)(p + (((lk)     ^ (r & 7)) << 3));
            bl[f] = *(const half8*)(p + (((lk + 4) ^ (r & 7)) << 3));
        }
#pragma unroll
        for (int i2 = 0; i2 < FM; ++i2)
#pragma unroll
            for (int j2 = 0; j2 < FN; ++j2) {
                acc[i2][j2] = __builtin_amdgcn_mfma_f32_16x16x32_f16(ah[i2], bh[j2], acc[i2][j2], 0, 0, 0);
                acc[i2][j2] = __builtin_amdgcn_mfma_f32_16x16x32_f16(ah[i2], bl[j2], acc[i2][j2], 0, 0, 0);
                acc[i2][j2] = __builtin_amdgcn_mfma_f32_16x16x32_f16(al[i2], bh[j2], acc[i2][j2], 0, 0, 0);
            }
        __syncthreads();
    }

    // ---- epilogue: C/D mapping col=lane&15, row=(lane>>4)*4+reg (m89) ----
#pragma unroll
    for (int f = 0; f < FM; ++f)
#pragma unroll
        for (int g = 0; g < FN; ++g) {
            int row = m0 + wm * (BM / 2) + f * 16 + (lane >> 4) * 4;
            int col = n0 + wn * (BN / 2) + g * 16 + (lane & 15);
#pragma unroll
            for (int j = 0; j < 4; ++j)
                C[(size_t)(row + j) * ldc + col] = acc[f][g][j];
        }
}

// ---------------------------------------------------------------------------
// Generic NT GEMM (fp32 VALU) for the small matmuls (x_proj, dt_proj).
__global__ __launch_bounds__(256) void gemm_nt(
    const float* __restrict__ A, int lda,
    const float* __restrict__ W, int ldw,
    float* __restrict__ C, int ldc,
    int M, int N, int K,
    const float* __restrict__ bias, int epi)
{
    __shared__ float As[16][64];
    __shared__ float Bs[16][64];
    int tid = threadIdx.x;
    int tx = tid & 15, ty = tid >> 4;
    int m0 = blockIdx.y * 64, n0 = blockIdx.x * 64;
    int lr = tid >> 2;
    int lc = (tid & 3) * 4;
    float acc[4][4] = {};

    for (int k0 = 0; k0 < K; k0 += 16) {
        float4 a4 = *(const float4*)(A + (size_t)(m0 + lr) * lda + k0 + lc);
        float4 b4 = *(const float4*)(W + (size_t)(n0 + lr) * ldw + k0 + lc);
        As[lc + 0][lr] = a4.x; As[lc + 1][lr] = a4.y;
        As[lc + 2][lr] = a4.z; As[lc + 3][lr] = a4.w;
        Bs[lc + 0][lr] = b4.x; Bs[lc + 1][lr] = b4.y;
        Bs[lc + 2][lr] = b4.z; Bs[lc + 3][lr] = b4.w;
        __syncthreads();
#pragma unroll
        for (int k = 0; k < 16; ++k) {
            float4 av = *(const float4*)&As[k][ty * 4];
            float4 bv = *(const float4*)&Bs[k][tx * 4];
            float a_[4] = {av.x, av.y, av.z, av.w};
            float b_[4] = {bv.x, bv.y, bv.z, bv.w};
#pragma unroll
            for (int i = 0; i < 4; ++i)
#pragma unroll
                for (int j = 0; j < 4; ++j)
                    acc[i][j] += a_[i] * b_[j];
        }
        __syncthreads();
    }

#pragma unroll
    for (int i = 0; i < 4; ++i) {
        int row = m0 + ty * 4 + i;
        int col = n0 + tx * 4;
        float v[4] = {acc[i][0], acc[i][1], acc[i][2], acc[i][3]};
        if (epi == 1) {
#pragma unroll
            for (int j = 0; j < 4; ++j) {
                float t = v[j] + bias[col + j];
                v[j] = (t > 20.f) ? t : log1pf(expf(t));
            }
        }
        float4 o = {v[0], v[1], v[2], v[3]};
        *(float4*)(C + (size_t)row * ldc + col) = o;
    }
}

// ---------------------------------------------------------------------------
// Causal depthwise conv (width 4) + bias + SiLU.
__global__ __launch_bounds__(256) void conv_silu(const float* __restrict__ xz,
                                                 const float* __restrict__ cw,
                                                 const float* __restrict__ cb,
                                                 float* __restrict__ xi) {
    int idx = blockIdx.x * 256 + threadIdx.x;
    int d = idx & 1023;
    int t = (idx >> 10) & 1023;
    int b = idx >> 20;
    const float* base = xz + (size_t)(b * LL) * (2 * DINNER) + d;
    float acc = cb[d];
#pragma unroll
    for (int j = 0; j < DCONV; ++j) {
        int tt = t - 3 + j;
        if (tt >= 0) acc += cw[d * 4 + j] * base[(size_t)tt * (2 * DINNER)];
    }
    float s = acc / (1.f + expf(-acc));
    xi[idx] = s;
}

// ---------------------------------------------------------------------------
// Selective scan, chunked: 8 chunks x 128 steps.
template <int PASS>
__global__ __launch_bounds__(256) void scan_k(
    const float* __restrict__ dlt, const float* __restrict__ xi,
    const float* __restrict__ dbc, const float* __restrict__ A_log,
    const float* __restrict__ Dskip, const float* __restrict__ xz,
    float* __restrict__ P, float* __restrict__ S,
    const float* __restrict__ H0, float* __restrict__ yg)
{
    __shared__ float sd[128][16], sx[128][16], sB[128][16], sC[128][16], sY[128][16];
    int c = blockIdx.x, dblk = blockIdx.y, b = blockIdx.z;
    int tid = threadIdx.x;
    int d0 = dblk * 16;
    int t0 = c * 128;

    for (int idx = tid; idx < 128 * 16; idx += 256) {
        int t = idx >> 4, i = idx & 15;
        int row = b * LL + t0 + t;
        sd[t][i] = dlt[(size_t)row * DINNER + d0 + i];
        sx[t][i] = xi[(size_t)row * DINNER + d0 + i];
        sB[t][i] = dbc[(size_t)row * 64 + DTRANK + i];
        sC[t][i] = dbc[(size_t)row * 64 + DTRANK + DSTATE + i];
    }
    __syncthreads();

    int di = tid >> 4, n = tid & 15;
    int d = d0 + di;
    float Adn = -expf(A_log[d * DSTATE + n]);
    float Dsk = Dskip[d];
    float h, ap = 1.f;
    if (PASS == 1) h = 0.f;
    else           h = H0[(size_t)(c * 2 + b) * 16384 + d * 16 + n];

    for (int t = 0; t < 128; ++t) {
        float dl = sd[t][di];
        float dA = expf(dl * Adn);
        h = dA * h + dl * sx[t][di] * sB[t][n];
        if (PASS == 1) {
            ap *= dA;
        } else {
            float p = h * sC[t][n];
            p += __shfl_xor(p, 1);
            p += __shfl_xor(p, 2);
            p += __shfl_xor(p, 4);
            p += __shfl_xor(p, 8);
            if (n == 0) sY[t][di] = p + sx[t][di] * Dsk;
        }
    }

    if (PASS == 1) {
        size_t o = (size_t)(c * 2 + b) * 16384 + d * 16 + n;
        P[o] = ap;
        S[o] = h;
    } else {
        __syncthreads();
        for (int idx = tid; idx < 128 * 16; idx += 256) {
            int t = idx >> 4, i = idx & 15;
            int row = b * LL + t0 + t;
            float z = xz[(size_t)row * (2 * DINNER) + DINNER + d0 + i];
            float y = sY[t][i];
            yg[(size_t)row * DINNER + d0 + i] = y * (z / (1.f + expf(-z)));
        }
    }
}

// Chunk-carry prefix.
__global__ __launch_bounds__(256) void scan_carry(const float* __restrict__ P,
                                                  const float* __restrict__ S,
                                                  float* __restrict__ H0) {
    int idx = blockIdx.x * 256 + threadIdx.x;
    float carry = 0.f;
#pragma unroll
    for (int c = 0; c < 8; ++c) {
        H0[(size_t)c * 32768 + idx] = carry;
        carry = P[(size_t)c * 32768 + idx] * carry + S[(size_t)c * 32768 + idx];
    }
}

// ---------------------------------------------------------------------------
// LayerNorm over last dim 512.
__global__ __launch_bounds__(128) void lnorm(const float* __restrict__ x,
                                             const float* __restrict__ w,
                                             const float* __restrict__ bp,
                                             float* __restrict__ xn) {
    int row = blockIdx.x;
    int tid = threadIdx.x;
    float4 v = *(const float4*)(x + (size_t)row * DMODEL + tid * 4);
    float s = v.x + v.y + v.z + v.w;
    float q = v.x * v.x + v.y * v.y + v.z * v.z + v.w * v.w;
#pragma unroll
    for (int m = 1; m < 64; m <<= 1) {
        s += __shfl_xor(s, m);
        q += __shfl_xor(q, m);
    }
    __shared__ float ss[2], qq[2];
    if ((tid & 63) == 0) { ss[tid >> 6] = s; qq[tid >> 6] = q; }
    __syncthreads();
    s = ss[0] + ss[1];
    q = qq[0] + qq[1];
    float mu = s / (float)DMODEL;
    float var = q / (float)DMODEL - mu * mu;
    float r = rsqrtf(var + 1e-5f);
    int c = tid * 4;
    float4 o;
    o.x = (v.x - mu) * r * w[c + 0] + bp[c + 0];
    o.y = (v.y - mu) * r * w[c + 1] + bp[c + 1];
    o.z = (v.z - mu) * r * w[c + 2] + bp[c + 2];
    o.w = (v.w - mu) * r * w[c + 3] + bp[c + 3];
    *(float4*)(xn + (size_t)row * DMODEL + c) = o;
}

// ---------------------------------------------------------------------------
extern "C" void kernel_launch(void* const* d_in, const int* in_sizes, int n_in,
                              void* d_out, int out_size, void* d_ws, size_t ws_size,
                              hipStream_t stream) {
    const int*   tokens = (const int*)d_in[0];
    const float* embed  = (const float*)d_in[1];
    const float* inw    = (const float*)d_in[2];
    const float* cw     = (const float*)d_in[3];
    const float* cb     = (const float*)d_in[4];
    const float* xpw    = (const float*)d_in[5];
    const float* dtw    = (const float*)d_in[6];
    const float* dtb    = (const float*)d_in[7];
    const float* Alog   = (const float*)d_in[8];
    const float* Dsk    = (const float*)d_in[9];
    const float* outw   = (const float*)d_in[10];
    const float* nw     = (const float*)d_in[11];
    const float* nb     = (const float*)d_in[12];
    const float* hw     = (const float*)d_in[13];
    float* out = (float*)d_out;

    float* ws = (float*)d_ws;
    float* x   = ws;                    // ROWS*DMODEL
    float* xz  = x   + (1 << 20);       // ROWS*2*DINNER
    float* xib = xz  + (4 << 20);       // ROWS*DINNER
    float* dbc = xib + (2 << 20);       // ROWS*64
    float* dlt = dbc + (1 << 17);       // ROWS*DINNER
    float* yg  = dlt + (2 << 20);       // ROWS*DINNER
    float* xn  = yg  + (2 << 20);       // ROWS*DMODEL
    float* Pb  = xn  + (1 << 20);       // 8*2*1024*16
    float* Sb  = Pb  + (1 << 18);
    float* H0  = Sb  + (1 << 18);

    embed_k<<<ROWS, 128, 0, stream>>>(tokens, embed, x);

    for (int l = 0; l < NLAYERS; ++l) {
        const float* inw_l  = inw  + (size_t)l * 2 * DINNER * DMODEL;
        const float* cw_l   = cw   + (size_t)l * DINNER * DCONV;
        const float* cb_l   = cb   + (size_t)l * DINNER;
        const float* xpw_l  = xpw  + (size_t)l * 64 * DINNER;
        const float* dtw_l  = dtw  + (size_t)l * DINNER * DTRANK;
        const float* dtb_l  = dtb  + (size_t)l * DINNER;
        const float* Alog_l = Alog + (size_t)l * DINNER * DSTATE;
        const float* Dsk_l  = Dsk  + (size_t)l * DINNER;
        const float* outw_l = outw + (size_t)l * DMODEL * DINNER;

        // xz = x @ inw^T   [2048, 2048], K=512 -> grid 16x16=256 blocks
        gemm_split<128, 128><<<16 * 16, 256, 0, stream>>>(
            x, DMODEL, inw_l, DMODEL, xz, 2 * DINNER, DMODEL, 16);
        // xi = silu(causal_conv(xz[:, :DINNER]) + cb)
        conv_silu<<<(ROWS * DINNER) / 256, 256, 0, stream>>>(xz, cw_l, cb_l, xib);
        // dbc = xi @ xpw^T   [2048, 64]  (fp32 VALU; keeps delta path exact)
        gemm_nt<<<dim3(1, ROWS / 64), 256, 0, stream>>>(
            xib, DINNER, xpw_l, DINNER, dbc, 64, ROWS, 64, DINNER, nullptr, 0);
        // delta = softplus(dbc[:, :32] @ dtw^T + dtb)   [2048, 1024]
        gemm_nt<<<dim3(DINNER / 64, ROWS / 64), 256, 0, stream>>>(
            dbc, 64, dtw_l, DTRANK, dlt, DINNER, ROWS, DINNER, DTRANK, dtb_l, 1);
        // selective scan (3 passes)
        scan_k<1><<<dim3(8, DINNER / 16, BB), 256, 0, stream>>>(
            dlt, xib, dbc, Alog_l, Dsk_l, xz, Pb, Sb, nullptr, nullptr);
        scan_carry<<<128, 256, 0, stream>>>(Pb, Sb, H0);
        scan_k<3><<<dim3(8, DINNER / 16, BB), 256, 0, stream>>>(
            dlt, xib, dbc, Alog_l, Dsk_l, xz, nullptr, nullptr, H0, yg);
        // x = yg @ outw^T   [2048, 512], K=1024 -> 64x64 tile, 32x8=256 blocks
        gemm_split<64, 64><<<32 * 8, 256, 0, stream>>>(
            yg, DINNER, outw_l, DINNER, x, DMODEL, DINNER, 8);
    }

    lnorm<<<ROWS, 128, 0, stream>>>(x, nw, nb, xn);
    // logits = xn @ head_w^T   [2048, 32000], K=512 -> grid 250x16=4000 blocks
    gemm_split<128, 128><<<250 * 16, 256, 0, stream>>>(
        xn, DMODEL, hw, DMODEL, out, VOCAB, DMODEL, 250);
}